// Round 1
// baseline (7489.919 us; speedup 1.0000x reference)
//
#include <hip/hip_runtime.h>

#define T_SEQ 256
#define DMODEL 1024
#define NHEAD 16
#define HSZ 64
#define NLAYER 12
#define VOCAB 50257
#define FF 4096
#define MROWS 2048

using short8 = __attribute__((ext_vector_type(8))) short;
using f32x4  = __attribute__((ext_vector_type(4))) float;

__device__ __forceinline__ float bf2f(unsigned short u) {
    unsigned int x = ((unsigned int)u) << 16;
    return __builtin_bit_cast(float, x);
}
__device__ __forceinline__ unsigned short f2bf(float f) {
    unsigned int u = __builtin_bit_cast(unsigned int, f);
    unsigned int r = (u + 0x7fffu + ((u >> 16) & 1u)) >> 16;
    return (unsigned short)r;
}
__device__ __forceinline__ void async_copy16(const void* g, void* l) {
    __builtin_amdgcn_global_load_lds(
        (const __attribute__((address_space(1))) unsigned int*)g,
        (__attribute__((address_space(3))) unsigned int*)l, 16, 0, 0);
}

// ---------------------------------------------------------------------------
// Embedding: x[row][d] = tok_emb[idx[row]][d] + pos_emb[row%T][d]
// ---------------------------------------------------------------------------
__global__ __launch_bounds__(256) void embed_kernel(
    const int* __restrict__ idx, const float* __restrict__ tok,
    const float* __restrict__ pos, float* __restrict__ x)
{
    int row = blockIdx.x, tid = threadIdx.x;
    int t = row & (T_SEQ - 1);
    int token = idx[row];
    float4 a = ((const float4*)(tok + (size_t)token * DMODEL))[tid];
    float4 p = ((const float4*)(pos + (size_t)t * DMODEL))[tid];
    float4 o;
    o.x = a.x + p.x; o.y = a.y + p.y; o.z = a.z + p.z; o.w = a.w + p.w;
    ((float4*)(x + (size_t)row * DMODEL))[tid] = o;
}

// ---------------------------------------------------------------------------
// LayerNorm: one block per row (256 thr x 4 elem), bf16 output
// ---------------------------------------------------------------------------
__global__ __launch_bounds__(256) void ln_kernel(
    const float* __restrict__ x, const float* __restrict__ g,
    const float* __restrict__ b, unsigned short* __restrict__ out)
{
    int row = blockIdx.x, tid = threadIdx.x;
    float4 v = ((const float4*)(x + (size_t)row * DMODEL))[tid];
    float s  = v.x + v.y + v.z + v.w;
    float ss = v.x * v.x + v.y * v.y + v.z * v.z + v.w * v.w;
    for (int o = 32; o > 0; o >>= 1) {
        s  += __shfl_down(s, o);
        ss += __shfl_down(ss, o);
    }
    __shared__ float ps[4], pss[4];
    int wave = tid >> 6, lane = tid & 63;
    if (lane == 0) { ps[wave] = s; pss[wave] = ss; }
    __syncthreads();
    float st  = ps[0] + ps[1] + ps[2] + ps[3];
    float sst = pss[0] + pss[1] + pss[2] + pss[3];
    float mu  = st * (1.0f / DMODEL);
    float var = sst * (1.0f / DMODEL) - mu * mu;
    float rstd = rsqrtf(var + 1e-5f);
    float4 gv = ((const float4*)g)[tid];
    float4 bv = ((const float4*)b)[tid];
    ushort4 o4;
    o4.x = f2bf((v.x - mu) * rstd * gv.x + bv.x);
    o4.y = f2bf((v.y - mu) * rstd * gv.y + bv.y);
    o4.z = f2bf((v.z - mu) * rstd * gv.z + bv.z);
    o4.w = f2bf((v.w - mu) * rstd * gv.w + bv.w);
    ((ushort4*)out)[(size_t)row * (DMODEL / 4) + tid] = o4;
}

// ---------------------------------------------------------------------------
// Generic bf16-MFMA GEMM: C[M,N] = A_bf16[M,K] @ B_f32[K,N] (+bias/relu/res)
// 128x128 tile, BK=64, 4 waves, 16x16x32 MFMA, XOR-swizzled LDS.
// bmode 0: B row-major with ldb.
// bmode 1: packed QKV: col n -> seg=n>>10 (B0/B1/B2), head=(n&1023)>>6,
//          s=n&63; element (k,n) at headbase + k*64 + s (stride 64).
// ---------------------------------------------------------------------------
__global__ __launch_bounds__(256) void gemm_kernel(
    const unsigned short* __restrict__ A, int lda,
    const float* __restrict__ B0, const float* __restrict__ B1,
    const float* __restrict__ B2, int bmode, int ldb,
    const float* __restrict__ bias,
    void* __restrict__ Cv, int ldc, int cbf16,
    const float* __restrict__ res, int ldr,
    int relu, int M, int N, int K)
{
    __shared__ __align__(16) char As[128 * 128];   // 128 rows x 128B (64 bf16)
    __shared__ __align__(16) char Bs[128 * 128];   // 128 cols x 128B (64 bf16)
    int tid = threadIdx.x;
    int wave = tid >> 6, lane = tid & 63;
    int wr = wave >> 1, wc = wave & 1;
    int m0 = blockIdx.y * 128, n0 = blockIdx.x * 128;

    f32x4 acc[4][4];
    for (int m = 0; m < 4; m++)
        for (int n = 0; n < 4; n++)
            acc[m][n] = (f32x4){0.f, 0.f, 0.f, 0.f};

    // B staging assignment: 4 pairs (n, kgroup) per thread
    const float* bptr[4];
    long cb[4];
    int bn[4], bkg[4];
    for (int i = 0; i < 4; i++) {
        int p = tid + i * 256;
        int n = p & 127, kg = p >> 7;
        bn[i] = n; bkg[i] = kg;
        int gn = n0 + n;
        if (gn < N) {
            if (bmode == 0) {
                bptr[i] = B0;
                cb[i] = (long)gn;
            } else {
                int seg = gn >> 10, nn = gn & 1023;
                bptr[i] = (seg == 0) ? B0 : (seg == 1) ? B1 : B2;
                cb[i] = (long)(nn >> 6) * (long)K * 64 + (long)(nn & 63);
            }
        } else { bptr[i] = B0; cb[i] = -1; }
    }
    long rstride = (bmode == 0) ? (long)ldb : 64;

    int ksw = (((lane & 7) ^ (lane >> 3)) << 4);  // pre-swizzled src k-byte
    int KT = K >> 6;
    for (int kt = 0; kt < KT; kt++) {
        int k0 = kt << 6;
        __syncthreads();
        // ---- stage A (global_load_lds, linear LDS dest, swizzled src) ----
        #pragma unroll
        for (int j = 0; j < 4; j++) {
            int row = (wave * 4 + j) * 8 + (lane >> 3);
            const char* src = (const char*)A + ((size_t)(m0 + row) * lda + k0) * 2 + ksw;
            char* dst = As + (wave * 4 + j) * 1024;  // wave-uniform base
            async_copy16(src, dst);
        }
        // ---- stage B (coalesced f32 loads, cvt, swizzled ds_write_b128) ----
        #pragma unroll
        for (int i = 0; i < 4; i++) {
            float f[8];
            if (cb[i] >= 0) {
                const float* bp = bptr[i] + cb[i] + (long)(k0 + bkg[i] * 8) * rstride;
                #pragma unroll
                for (int j = 0; j < 8; j++) f[j] = bp[(long)j * rstride];
            } else {
                #pragma unroll
                for (int j = 0; j < 8; j++) f[j] = 0.f;
            }
            unsigned int w0 = (unsigned int)f2bf(f[0]) | ((unsigned int)f2bf(f[1]) << 16);
            unsigned int w1 = (unsigned int)f2bf(f[2]) | ((unsigned int)f2bf(f[3]) << 16);
            unsigned int w2 = (unsigned int)f2bf(f[4]) | ((unsigned int)f2bf(f[5]) << 16);
            unsigned int w3 = (unsigned int)f2bf(f[6]) | ((unsigned int)f2bf(f[7]) << 16);
            int n = bn[i];
            int off = n * 128 + ((bkg[i] * 16) ^ ((n & 7) << 4));
            uint4 val; val.x = w0; val.y = w1; val.z = w2; val.w = w3;
            *(uint4*)(void*)(Bs + off) = val;
        }
        __syncthreads();  // implicit vmcnt(0)+lgkmcnt(0) drain
        // ---- MFMA compute ----
        #pragma unroll
        for (int ks = 0; ks < 2; ks++) {
            int kb = ks * 64 + ((lane >> 4) << 4);
            short8 a[4], b[4];
            #pragma unroll
            for (int m = 0; m < 4; m++) {
                int r = wr * 64 + m * 16 + (lane & 15);
                a[m] = *(const short8*)(const void*)(As + r * 128 + (kb ^ ((r & 7) << 4)));
            }
            #pragma unroll
            for (int n = 0; n < 4; n++) {
                int c = wc * 64 + n * 16 + (lane & 15);
                b[n] = *(const short8*)(const void*)(Bs + c * 128 + (kb ^ ((c & 7) << 4)));
            }
            #pragma unroll
            for (int m = 0; m < 4; m++)
                #pragma unroll
                for (int n = 0; n < 4; n++)
                    acc[m][n] = __builtin_amdgcn_mfma_f32_16x16x32_bf16(a[m], b[n], acc[m][n], 0, 0, 0);
        }
    }
    // ---- epilogue: D row=(lane>>4)*4+reg, col=lane&15 ----
    #pragma unroll
    for (int m = 0; m < 4; m++) {
        int rowb = m0 + wr * 64 + m * 16 + ((lane >> 4) << 2);
        #pragma unroll
        for (int n = 0; n < 4; n++) {
            int col = n0 + wc * 64 + n * 16 + (lane & 15);
            if (col < N) {
                float bi = bias ? bias[col] : 0.f;
                #pragma unroll
                for (int r2 = 0; r2 < 4; r2++) {
                    float v = acc[m][n][r2] + bi;
                    if (relu) v = fmaxf(v, 0.f);
                    int row = rowb + r2;
                    if (ldr >= 0) v += res[(size_t)row * ldr + col];
                    if (cbf16) ((unsigned short*)Cv)[(size_t)row * ldc + col] = f2bf(v);
                    else       ((float*)Cv)[(size_t)row * ldc + col] = v;
                }
            }
        }
    }
}

// ---------------------------------------------------------------------------
// Attention scores+softmax: block per (b,h,t); thread u computes one score
// ---------------------------------------------------------------------------
__global__ __launch_bounds__(256) void attn_scores_kernel(
    const unsigned short* __restrict__ qkv, float* __restrict__ sc)
{
    int t  = blockIdx.x & (T_SEQ - 1);
    int bh = blockIdx.x >> 8;
    int b = bh >> 4, hh = bh & 15;
    int tid = threadIdx.x;
    __shared__ float qf[HSZ];
    __shared__ float red[256];
    size_t qoff = ((size_t)(b * T_SEQ + t) * 3072) + (size_t)hh * HSZ;
    if (tid < HSZ) qf[tid] = bf2f(qkv[qoff + tid]);
    __syncthreads();
    int u = tid;
    size_t koff = ((size_t)(b * T_SEQ + u) * 3072) + 1024 + (size_t)hh * HSZ;
    const uint4* kp = (const uint4*)(qkv + koff);
    float s = 0.f;
    #pragma unroll
    for (int j = 0; j < 8; j++) {
        uint4 kv = kp[j];
        const unsigned short* ku = (const unsigned short*)&kv;
        #pragma unroll
        for (int e = 0; e < 8; e++) s += qf[j * 8 + e] * bf2f(ku[e]);
    }
    s *= 0.125f;  // 1/sqrt(64)
    bool valid = (u <= t);
    red[tid] = valid ? s : -3.4e38f;
    __syncthreads();
    for (int o = 128; o > 0; o >>= 1) {
        if (tid < o) red[tid] = fmaxf(red[tid], red[tid + o]);
        __syncthreads();
    }
    float mx = red[0];
    __syncthreads();
    float e = valid ? __expf(s - mx) : 0.f;
    red[tid] = e;
    __syncthreads();
    for (int o = 128; o > 0; o >>= 1) {
        if (tid < o) red[tid] += red[tid + o];
        __syncthreads();
    }
    float inv = 1.f / red[0];
    sc[((size_t)bh * T_SEQ + t) * T_SEQ + u] = e * inv;
}

// ---------------------------------------------------------------------------
// PV: block per (b,h,t), 64 lanes over head dim; adds into residual x
// ---------------------------------------------------------------------------
__global__ __launch_bounds__(64) void attn_pv_kernel(
    const unsigned short* __restrict__ qkv, const float* __restrict__ sc,
    float* __restrict__ x)
{
    int t  = blockIdx.x & (T_SEQ - 1);
    int bh = blockIdx.x >> 8;
    int b = bh >> 4, hh = bh & 15;
    int si = threadIdx.x;
    __shared__ float p[T_SEQ];
    const float* pr = sc + ((size_t)bh * T_SEQ + t) * T_SEQ;
    for (int j = si; j < T_SEQ; j += 64) p[j] = pr[j];
    __syncthreads();
    float o = 0.f;
    size_t vbase = ((size_t)(b * T_SEQ)) * 3072 + 2048 + (size_t)hh * HSZ + si;
    for (int u = 0; u <= t; u++) o += p[u] * bf2f(qkv[vbase + (size_t)u * 3072]);
    x[((size_t)(b * T_SEQ + t)) * DMODEL + hh * HSZ + si] += o;
}

// ---------------------------------------------------------------------------
// Loss pass 1: per-row online logsumexp -> nll[row]
// ---------------------------------------------------------------------------
__global__ __launch_bounds__(256) void loss1_kernel(
    const float* __restrict__ logits, const int* __restrict__ targets,
    float* __restrict__ nll)
{
    int r = blockIdx.x, tid = threadIdx.x;
    const float* row = logits + (size_t)r * VOCAB;
    float m = -3.4e38f, s = 0.f;
    for (int v = tid; v < VOCAB; v += 256) {
        float xv = row[v];
        float nm = fmaxf(m, xv);
        s = s * __expf(m - nm) + __expf(xv - nm);
        m = nm;
    }
    __shared__ float ms[256], ssh[256];
    ms[tid] = m; ssh[tid] = s;
    __syncthreads();
    for (int o = 128; o > 0; o >>= 1) {
        if (tid < o) {
            float m1 = ms[tid], s1 = ssh[tid];
            float m2 = ms[tid + o], s2 = ssh[tid + o];
            float nm = fmaxf(m1, m2);
            ssh[tid] = s1 * __expf(m1 - nm) + s2 * __expf(m2 - nm);
            ms[tid] = nm;
        }
        __syncthreads();
    }
    if (tid == 0) nll[r] = logf(ssh[0]) + ms[0] - row[targets[r]];
}

// ---------------------------------------------------------------------------
// Loss pass 2: deterministic mean over 2048 rows
// ---------------------------------------------------------------------------
__global__ __launch_bounds__(256) void loss2_kernel(
    const float* __restrict__ nll, float* __restrict__ out)
{
    int tid = threadIdx.x;
    float s = 0.f;
    for (int i = tid; i < MROWS; i += 256) s += nll[i];
    __shared__ float red[256];
    red[tid] = s;
    __syncthreads();
    for (int o = 128; o > 0; o >>= 1) {
        if (tid < o) red[tid] += red[tid + o];
        __syncthreads();
    }
    if (tid == 0) out[0] = red[0] * (1.0f / MROWS);
}

// ---------------------------------------------------------------------------
extern "C" void kernel_launch(void* const* d_in, const int* in_sizes, int n_in,
                              void* d_out, int out_size, void* d_ws, size_t ws_size,
                              hipStream_t stream)
{
    const int*   idx  = (const int*)d_in[0];
    const int*   tgt  = (const int*)d_in[1];
    const float* tok  = (const float*)d_in[2];
    const float* pos  = (const float*)d_in[3];
    const float* Wq   = (const float*)d_in[4];
    const float* Wk   = (const float*)d_in[5];
    const float* Wv   = (const float*)d_in[6];
    const float* ln1g = (const float*)d_in[7];
    const float* ln1b = (const float*)d_in[8];
    const float* ln2g = (const float*)d_in[9];
    const float* ln2b = (const float*)d_in[10];
    const float* fc1w = (const float*)d_in[11];
    const float* fc1b = (const float*)d_in[12];
    const float* fc2w = (const float*)d_in[13];
    const float* fc2b = (const float*)d_in[14];
    const float* lnfg = (const float*)d_in[15];
    const float* lnfb = (const float*)d_in[16];
    const float* lmw  = (const float*)d_in[17];
    const float* lmb  = (const float*)d_in[18];

    char* ws = (char*)d_ws;
    float*          x   = (float*)(ws + 0);                  // 8.39 MB f32 [2048,1024]
    unsigned short* h   = (unsigned short*)(ws + 8388608);   // 4.19 MB bf16 [2048,1024]
    unsigned short* qkv = (unsigned short*)(ws + 12582912);  // 12.6 MB bf16 [2048,3072]
    float*          sc  = (float*)(ws + 25165824);           // 33.6 MB f32 [128,256,256]
    unsigned short* mid = (unsigned short*)(ws + 58720256);  // 16.8 MB bf16 [2048,4096]
    float*          nll = (float*)(ws + 75497472);           // 8 KB
    float* logits = (float*)d_out;
    float* lossp  = logits + (size_t)MROWS * VOCAB;

    embed_kernel<<<MROWS, 256, 0, stream>>>(idx, tok, pos, x);

    for (int l = 0; l < NLAYER; l++) {
        ln_kernel<<<MROWS, 256, 0, stream>>>(x, ln1g + l * DMODEL, ln1b + l * DMODEL, h);
        // QKV packed: N=3072 (seg 0/1/2 -> Wq/Wk/Wv), bf16 out
        gemm_kernel<<<dim3(24, 16), 256, 0, stream>>>(
            h, DMODEL,
            Wq + (size_t)l * NHEAD * DMODEL * HSZ,
            Wk + (size_t)l * NHEAD * DMODEL * HSZ,
            Wv + (size_t)l * NHEAD * DMODEL * HSZ,
            1, 0, nullptr,
            qkv, 3072, 1, nullptr, -1, 0,
            MROWS, 3072, DMODEL);
        attn_scores_kernel<<<32768, 256, 0, stream>>>(qkv, sc);
        attn_pv_kernel<<<32768, 64, 0, stream>>>(qkv, sc, x);
        ln_kernel<<<MROWS, 256, 0, stream>>>(x, ln2g + l * DMODEL, ln2b + l * DMODEL, h);
        // fc1 + relu, bf16 out
        gemm_kernel<<<dim3(32, 16), 256, 0, stream>>>(
            h, DMODEL,
            fc1w + (size_t)l * DMODEL * FF, nullptr, nullptr,
            0, FF, fc1b + (size_t)l * FF,
            mid, FF, 1, nullptr, -1, 1,
            MROWS, FF, DMODEL);
        // fc2 + residual add into x (f32)
        gemm_kernel<<<dim3(8, 16), 256, 0, stream>>>(
            mid, FF,
            fc2w + (size_t)l * FF * DMODEL, nullptr, nullptr,
            0, DMODEL, fc2b + (size_t)l * DMODEL,
            x, DMODEL, 0, x, DMODEL, 0,
            MROWS, DMODEL, FF);
    }

    ln_kernel<<<MROWS, 256, 0, stream>>>(x, lnfg, lnfb, h);
    // LM head: N=50257 (tail-guarded), f32 out to d_out
    gemm_kernel<<<dim3(393, 16), 256, 0, stream>>>(
        h, DMODEL,
        lmw, nullptr, nullptr,
        0, VOCAB, lmb,
        logits, VOCAB, 0, nullptr, -1, 0,
        MROWS, VOCAB, DMODEL);

    loss1_kernel<<<MROWS, 256, 0, stream>>>(logits, tgt, nll);
    loss2_kernel<<<1, 256, 0, stream>>>(nll, lossp);
}

// Round 2
// 5133.199 us; speedup vs baseline: 1.4591x; 1.4591x over previous
//
#include <hip/hip_runtime.h>

#define T_SEQ 256
#define DMODEL 1024
#define NHEAD 16
#define HSZ 64
#define NLAYER 12
#define VOCAB 50257
#define VPAD 50304
#define FF 4096
#define MROWS 2048

using short8 = __attribute__((ext_vector_type(8))) short;
using f32x4  = __attribute__((ext_vector_type(4))) float;

__device__ __forceinline__ float bf2f(unsigned short u) {
    unsigned int x = ((unsigned int)u) << 16;
    return __builtin_bit_cast(float, x);
}
__device__ __forceinline__ unsigned short f2bf(float f) {
    unsigned int u = __builtin_bit_cast(unsigned int, f);
    unsigned int r = (u + 0x7fffu + ((u >> 16) & 1u)) >> 16;
    return (unsigned short)r;
}
__device__ __forceinline__ void async_copy16(const void* g, void* l) {
    __builtin_amdgcn_global_load_lds(
        (const __attribute__((address_space(1))) unsigned int*)g,
        (__attribute__((address_space(3))) unsigned int*)l, 16, 0, 0);
}

// ---------------------------------------------------------------------------
// Embedding
// ---------------------------------------------------------------------------
__global__ __launch_bounds__(256) void embed_kernel(
    const int* __restrict__ idx, const float* __restrict__ tok,
    const float* __restrict__ pos, float* __restrict__ x)
{
    int row = blockIdx.x, tid = threadIdx.x;
    int t = row & (T_SEQ - 1);
    int token = idx[row];
    float4 a = ((const float4*)(tok + (size_t)token * DMODEL))[tid];
    float4 p = ((const float4*)(pos + (size_t)t * DMODEL))[tid];
    float4 o;
    o.x = a.x + p.x; o.y = a.y + p.y; o.z = a.z + p.z; o.w = a.w + p.w;
    ((float4*)(x + (size_t)row * DMODEL))[tid] = o;
}

// ---------------------------------------------------------------------------
// LayerNorm: one block per row, bf16 output
// ---------------------------------------------------------------------------
__global__ __launch_bounds__(256) void ln_kernel(
    const float* __restrict__ x, const float* __restrict__ g,
    const float* __restrict__ b, unsigned short* __restrict__ out)
{
    int row = blockIdx.x, tid = threadIdx.x;
    float4 v = ((const float4*)(x + (size_t)row * DMODEL))[tid];
    float s  = v.x + v.y + v.z + v.w;
    float ss = v.x * v.x + v.y * v.y + v.z * v.z + v.w * v.w;
    for (int o = 32; o > 0; o >>= 1) {
        s  += __shfl_down(s, o);
        ss += __shfl_down(ss, o);
    }
    __shared__ float ps[4], pss[4];
    int wave = tid >> 6, lane = tid & 63;
    if (lane == 0) { ps[wave] = s; pss[wave] = ss; }
    __syncthreads();
    float st  = ps[0] + ps[1] + ps[2] + ps[3];
    float sst = pss[0] + pss[1] + pss[2] + pss[3];
    float mu  = st * (1.0f / DMODEL);
    float var = sst * (1.0f / DMODEL) - mu * mu;
    float rstd = rsqrtf(var + 1e-5f);
    float4 gv = ((const float4*)g)[tid];
    float4 bv = ((const float4*)b)[tid];
    ushort4 o4;
    o4.x = f2bf((v.x - mu) * rstd * gv.x + bv.x);
    o4.y = f2bf((v.y - mu) * rstd * gv.y + bv.y);
    o4.z = f2bf((v.z - mu) * rstd * gv.z + bv.z);
    o4.w = f2bf((v.w - mu) * rstd * gv.w + bv.w);
    ((ushort4*)out)[(size_t)row * (DMODEL / 4) + tid] = o4;
}

// ---------------------------------------------------------------------------
// Weight transpose: in [R,C] f32 (per layer) -> out [C,R] bf16 (per layer)
// ---------------------------------------------------------------------------
__global__ __launch_bounds__(256) void wtranspose_kernel(
    const float* __restrict__ in, unsigned short* __restrict__ out,
    int R, int C, long in_l, long out_l)
{
    int lyr = blockIdx.z;
    in  += (size_t)lyr * in_l;
    out += (size_t)lyr * out_l;
    __shared__ float tile[32][33];
    int tx = threadIdx.x & 31, ty = threadIdx.x >> 5;
    int c0 = blockIdx.x * 32, r0 = blockIdx.y * 32;
    #pragma unroll
    for (int i = 0; i < 4; i++) {
        int r = r0 + ty + i * 8, c = c0 + tx;
        tile[ty + i * 8][tx] = (c < C) ? in[(size_t)r * C + c] : 0.f;
    }
    __syncthreads();
    #pragma unroll
    for (int i = 0; i < 4; i++) {
        int c = c0 + ty + i * 8, r = r0 + tx;
        if (c < C) out[(size_t)c * R + r] = f2bf(tile[tx][ty + i * 8]);
    }
}

// ---------------------------------------------------------------------------
// QKV weight pack: Wq/Wk/Wv [H,D,HS] f32 -> out[n, d] bf16, n=seg*1024+h*64+s
// grid: x = D/32, y = HS/32, z = nl*48 + seg*16 + h
// ---------------------------------------------------------------------------
__global__ __launch_bounds__(256) void qkvpack_kernel(
    const float* __restrict__ Wq, const float* __restrict__ Wk,
    const float* __restrict__ Wv, unsigned short* __restrict__ out,
    long w_l, long out_l)
{
    int z = blockIdx.z;
    int lyr = z / 48, r48 = z % 48;
    int seg = r48 >> 4, hh = r48 & 15;
    const float* W = (seg == 0 ? Wq : seg == 1 ? Wk : Wv)
                     + (size_t)lyr * w_l + (size_t)hh * DMODEL * HSZ;
    unsigned short* o = out + (size_t)lyr * out_l
                      + (size_t)(seg * 1024 + hh * 64) * DMODEL;
    __shared__ float tile[32][33];
    int tx = threadIdx.x & 31, ty = threadIdx.x >> 5;
    int d0 = blockIdx.x * 32, s0 = blockIdx.y * 32;
    #pragma unroll
    for (int i = 0; i < 4; i++)
        tile[ty + i * 8][tx] = W[(size_t)(d0 + ty + i * 8) * HSZ + s0 + tx];
    __syncthreads();
    #pragma unroll
    for (int i = 0; i < 4; i++)
        o[(size_t)(s0 + ty + i * 8) * DMODEL + d0 + tx] = f2bf(tile[tx][ty + i * 8]);
}

// ---------------------------------------------------------------------------
// bf16 MFMA GEMM: C[2048,N] = A[2048,K] @ Bt[N,K]^T  (both bf16, both via
// global_load_lds with XOR-swizzled source). BM = MF*32, BN=128, BK=64.
// ---------------------------------------------------------------------------
template<int MF>
__global__ __launch_bounds__(256) void gemm_bf16(
    const unsigned short* __restrict__ A, int lda,
    const unsigned short* __restrict__ Bt, int ldb,
    const float* __restrict__ bias,
    void* __restrict__ Cv, int ldc, int cbf16,
    const float* __restrict__ res, int ldr,
    int relu, int N, int K)
{
    constexpr int BM = MF * 32;
    __shared__ __align__(16) char As[BM * 128];
    __shared__ __align__(16) char Bs[128 * 128];
    int tid = threadIdx.x;
    int wave = tid >> 6, lane = tid & 63;
    int wr = wave >> 1, wc = wave & 1;
    int m0 = blockIdx.x * BM, n0 = blockIdx.y * 128;

    f32x4 acc[MF][4];
    #pragma unroll
    for (int m = 0; m < MF; m++)
        #pragma unroll
        for (int n = 0; n < 4; n++)
            acc[m][n] = (f32x4){0.f, 0.f, 0.f, 0.f};

    int ksw = (((lane & 7) ^ (lane >> 3)) << 4);  // pre-swizzled src k-byte
    int KT = K >> 6;
    for (int kt = 0; kt < KT; kt++) {
        int k0 = kt << 6;
        __syncthreads();
        #pragma unroll
        for (int j = 0; j < MF; j++) {
            int row = (wave * MF + j) * 8 + (lane >> 3);
            const char* src = (const char*)A + ((size_t)(m0 + row) * lda + k0) * 2 + ksw;
            async_copy16(src, As + (wave * MF + j) * 1024);
        }
        #pragma unroll
        for (int j = 0; j < 4; j++) {
            int nrow = (wave * 4 + j) * 8 + (lane >> 3);
            const char* src = (const char*)Bt + ((size_t)(n0 + nrow) * ldb + k0) * 2 + ksw;
            async_copy16(src, Bs + (wave * 4 + j) * 1024);
        }
        __syncthreads();  // compiler emits vmcnt(0) drain before barrier
        #pragma unroll
        for (int ks = 0; ks < 2; ks++) {
            int kb = ks * 64 + ((lane >> 4) << 4);
            short8 a[MF], b[4];
            #pragma unroll
            for (int m = 0; m < MF; m++) {
                int r = wr * (MF * 16) + m * 16 + (lane & 15);
                a[m] = *(const short8*)(const void*)(As + r * 128 + (kb ^ ((r & 7) << 4)));
            }
            #pragma unroll
            for (int n = 0; n < 4; n++) {
                int c = wc * 64 + n * 16 + (lane & 15);
                b[n] = *(const short8*)(const void*)(Bs + c * 128 + (kb ^ ((c & 7) << 4)));
            }
            #pragma unroll
            for (int m = 0; m < MF; m++)
                #pragma unroll
                for (int n = 0; n < 4; n++)
                    acc[m][n] = __builtin_amdgcn_mfma_f32_16x16x32_bf16(a[m], b[n], acc[m][n], 0, 0, 0);
        }
    }
    #pragma unroll
    for (int m = 0; m < MF; m++) {
        int rowb = m0 + wr * (MF * 16) + m * 16 + ((lane >> 4) << 2);
        #pragma unroll
        for (int n = 0; n < 4; n++) {
            int col = n0 + wc * 64 + n * 16 + (lane & 15);
            if (col < N) {
                float bi = bias ? bias[col] : 0.f;
                #pragma unroll
                for (int r2 = 0; r2 < 4; r2++) {
                    float v = acc[m][n][r2] + bi;
                    if (relu) v = fmaxf(v, 0.f);
                    int row = rowb + r2;
                    if (ldr >= 0) v += res[(size_t)row * ldr + col];
                    if (cbf16) ((unsigned short*)Cv)[(size_t)row * ldc + col] = f2bf(v);
                    else       ((float*)Cv)[(size_t)row * ldc + col] = v;
                }
            }
        }
    }
}

// ---------------------------------------------------------------------------
// Attention scores+softmax: block per (b,h,t); thread u computes one score
// ---------------------------------------------------------------------------
__global__ __launch_bounds__(256) void attn_scores_kernel(
    const unsigned short* __restrict__ qkv, float* __restrict__ sc)
{
    int t  = blockIdx.x & (T_SEQ - 1);
    int bh = blockIdx.x >> 8;
    int b = bh >> 4, hh = bh & 15;
    int tid = threadIdx.x;
    int wave = tid >> 6, lane = tid & 63;
    __shared__ float qf[HSZ];
    __shared__ float pmax[4], psum[4];
    size_t qoff = ((size_t)(b * T_SEQ + t) * 3072) + (size_t)hh * HSZ;
    if (tid < HSZ) qf[tid] = bf2f(qkv[qoff + tid]);
    __syncthreads();
    int u = tid;
    size_t koff = ((size_t)(b * T_SEQ + u) * 3072) + 1024 + (size_t)hh * HSZ;
    const uint4* kp = (const uint4*)(qkv + koff);
    float s = 0.f;
    #pragma unroll
    for (int j = 0; j < 8; j++) {
        uint4 kv = kp[j];
        const unsigned short* ku = (const unsigned short*)&kv;
        #pragma unroll
        for (int e = 0; e < 8; e++) s += qf[j * 8 + e] * bf2f(ku[e]);
    }
    s *= 0.125f;
    bool valid = (u <= t);
    float m = valid ? s : -3.4e38f;
    #pragma unroll
    for (int o = 32; o > 0; o >>= 1) m = fmaxf(m, __shfl_xor(m, o));
    if (lane == 0) pmax[wave] = m;
    __syncthreads();
    float mx = fmaxf(fmaxf(pmax[0], pmax[1]), fmaxf(pmax[2], pmax[3]));
    float e = valid ? __expf(s - mx) : 0.f;
    float se = e;
    #pragma unroll
    for (int o = 32; o > 0; o >>= 1) se += __shfl_xor(se, o);
    if (lane == 0) psum[wave] = se;
    __syncthreads();
    float tot = psum[0] + psum[1] + psum[2] + psum[3];
    sc[((size_t)bh * T_SEQ + t) * T_SEQ + u] = e * (1.f / tot);
}

// ---------------------------------------------------------------------------
// PV: block per (b,h,t); 4 waves split the u range; adds into residual x
// ---------------------------------------------------------------------------
__global__ __launch_bounds__(256) void attn_pv_kernel(
    const unsigned short* __restrict__ qkv, const float* __restrict__ sc,
    float* __restrict__ x)
{
    int t  = blockIdx.x & (T_SEQ - 1);
    int bh = blockIdx.x >> 8;
    int b = bh >> 4, hh = bh & 15;
    int tid = threadIdx.x;
    int si = tid & 63, w = tid >> 6;
    __shared__ float p[T_SEQ];
    __shared__ float op[4][HSZ];
    const float* pr = sc + ((size_t)bh * T_SEQ + t) * T_SEQ;
    p[tid] = pr[tid];  // p[u>t] == 0 by construction
    __syncthreads();
    float o = 0.f;
    size_t vbase = ((size_t)(b * T_SEQ + w * 64)) * 3072 + 2048 + (size_t)hh * HSZ + si;
    #pragma unroll 8
    for (int j = 0; j < 64; j++)
        o += p[w * 64 + j] * bf2f(qkv[vbase + (size_t)j * 3072]);
    op[w][si] = o;
    __syncthreads();
    if (tid < HSZ) {
        float r = op[0][tid] + op[1][tid] + op[2][tid] + op[3][tid];
        x[((size_t)(b * T_SEQ + t)) * DMODEL + hh * HSZ + tid] += r;
    }
}

// ---------------------------------------------------------------------------
// Loss pass 1: per-row online logsumexp -> nll[row]
// ---------------------------------------------------------------------------
__global__ __launch_bounds__(256) void loss1_kernel(
    const float* __restrict__ logits, const int* __restrict__ targets,
    float* __restrict__ nll)
{
    int r = blockIdx.x, tid = threadIdx.x;
    const float* row = logits + (size_t)r * VOCAB;
    float m = -3.4e38f, s = 0.f;
    for (int v = tid; v < VOCAB; v += 256) {
        float xv = row[v];
        float nm = fmaxf(m, xv);
        s = s * __expf(m - nm) + __expf(xv - nm);
        m = nm;
    }
    __shared__ float ms[256], ssh[256];
    ms[tid] = m; ssh[tid] = s;
    __syncthreads();
    for (int o = 128; o > 0; o >>= 1) {
        if (tid < o) {
            float m1 = ms[tid], s1 = ssh[tid];
            float m2 = ms[tid + o], s2 = ssh[tid + o];
            float nm = fmaxf(m1, m2);
            ssh[tid] = s1 * __expf(m1 - nm) + s2 * __expf(m2 - nm);
            ms[tid] = nm;
        }
        __syncthreads();
    }
    if (tid == 0) nll[r] = logf(ssh[0]) + ms[0] - row[targets[r]];
}

__global__ __launch_bounds__(256) void loss2_kernel(
    const float* __restrict__ nll, float* __restrict__ out)
{
    int tid = threadIdx.x;
    float s = 0.f;
    for (int i = tid; i < MROWS; i += 256) s += nll[i];
    __shared__ float red[256];
    red[tid] = s;
    __syncthreads();
    for (int o = 128; o > 0; o >>= 1) {
        if (tid < o) red[tid] += red[tid + o];
        __syncthreads();
    }
    if (tid == 0) out[0] = red[0] * (1.0f / MROWS);
}

// ---------------------------------------------------------------------------
extern "C" void kernel_launch(void* const* d_in, const int* in_sizes, int n_in,
                              void* d_out, int out_size, void* d_ws, size_t ws_size,
                              hipStream_t stream)
{
    const int*   idx  = (const int*)d_in[0];
    const int*   tgt  = (const int*)d_in[1];
    const float* tok  = (const float*)d_in[2];
    const float* pos  = (const float*)d_in[3];
    const float* Wq   = (const float*)d_in[4];
    const float* Wk   = (const float*)d_in[5];
    const float* Wv   = (const float*)d_in[6];
    const float* ln1g = (const float*)d_in[7];
    const float* ln1b = (const float*)d_in[8];
    const float* ln2g = (const float*)d_in[9];
    const float* ln2b = (const float*)d_in[10];
    const float* fc1w = (const float*)d_in[11];
    const float* fc1b = (const float*)d_in[12];
    const float* fc2w = (const float*)d_in[13];
    const float* fc2b = (const float*)d_in[14];
    const float* lnfg = (const float*)d_in[15];
    const float* lnfb = (const float*)d_in[16];
    const float* lmw  = (const float*)d_in[17];
    const float* lmb  = (const float*)d_in[18];

    char* ws = (char*)d_ws;
    float*          x    = (float*)(ws + 0);                  // [2048,1024] f32
    unsigned short* h    = (unsigned short*)(ws + 8388608);   // [2048,1024] bf16
    unsigned short* qkv  = (unsigned short*)(ws + 12582912);  // [2048,3072] bf16
    float*          sc   = (float*)(ws + 25165824);           // [128,256,256] f32
    unsigned short* mid  = (unsigned short*)(ws + 58720256);  // [2048,4096] bf16
    float*          nll  = (float*)(ws + 75497472);           // 8 KB
    unsigned short* lmwt = (unsigned short*)(ws + 75505664);  // [50304,1024] bf16
    // after lmwt: offset 178528256
    const size_t UP_NEED = 455352320ull;
    bool upfront = (ws_size >= UP_NEED);
    unsigned short* qkvt = (unsigned short*)(ws + 178528256);
    unsigned short* fc1t, * fc2t;
    long qkvt_l, fc1t_l, fc2t_l;
    if (upfront) {
        fc1t = (unsigned short*)(ws + 254025728);
        fc2t = (unsigned short*)(ws + 354689024);
        qkvt_l = 3072 * 1024; fc1t_l = (long)FF * 1024; fc2t_l = (long)1024 * FF;
    } else {
        fc1t = (unsigned short*)(ws + 184819712);
        fc2t = (unsigned short*)(ws + 193208320);
        qkvt_l = 0; fc1t_l = 0; fc2t_l = 0;
    }
    float* logits = (float*)d_out;
    float* lossp  = logits + (size_t)MROWS * VOCAB;

    // ---- weight conversion ----
    const long WQKV_L = (long)NHEAD * DMODEL * HSZ;
    if (upfront) {
        qkvpack_kernel<<<dim3(32, 2, 48 * NLAYER), 256, 0, stream>>>(
            Wq, Wk, Wv, qkvt, WQKV_L, qkvt_l);
        wtranspose_kernel<<<dim3(128, 32, NLAYER), 256, 0, stream>>>(
            fc1w, fc1t, DMODEL, FF, (long)DMODEL * FF, fc1t_l);
        wtranspose_kernel<<<dim3(32, 128, NLAYER), 256, 0, stream>>>(
            fc2w, fc2t, FF, DMODEL, (long)FF * DMODEL, fc2t_l);
    }
    wtranspose_kernel<<<dim3(1571, 32, 1), 256, 0, stream>>>(
        lmw, lmwt, DMODEL, VOCAB, 0, 0);

    embed_kernel<<<MROWS, 256, 0, stream>>>(idx, tok, pos, x);

    for (int l = 0; l < NLAYER; l++) {
        unsigned short* qkvt_p = qkvt + (size_t)l * qkvt_l;
        unsigned short* fc1t_p = fc1t + (size_t)l * fc1t_l;
        unsigned short* fc2t_p = fc2t + (size_t)l * fc2t_l;
        if (!upfront) {
            qkvpack_kernel<<<dim3(32, 2, 48), 256, 0, stream>>>(
                Wq + (size_t)l * WQKV_L, Wk + (size_t)l * WQKV_L,
                Wv + (size_t)l * WQKV_L, qkvt, WQKV_L, 0);
            wtranspose_kernel<<<dim3(128, 32, 1), 256, 0, stream>>>(
                fc1w + (size_t)l * DMODEL * FF, fc1t, DMODEL, FF, 0, 0);
            wtranspose_kernel<<<dim3(32, 128, 1), 256, 0, stream>>>(
                fc2w + (size_t)l * FF * DMODEL, fc2t, FF, DMODEL, 0, 0);
        }
        ln_kernel<<<MROWS, 256, 0, stream>>>(x, ln1g + l * DMODEL, ln1b + l * DMODEL, h);
        gemm_bf16<4><<<dim3(16, 24), 256, 0, stream>>>(
            h, DMODEL, qkvt_p, DMODEL, nullptr,
            qkv, 3072, 1, nullptr, -1, 0, 3072, DMODEL);
        attn_scores_kernel<<<32768, 256, 0, stream>>>(qkv, sc);
        attn_pv_kernel<<<32768, 256, 0, stream>>>(qkv, sc, x);
        ln_kernel<<<MROWS, 256, 0, stream>>>(x, ln2g + l * DMODEL, ln2b + l * DMODEL, h);
        gemm_bf16<4><<<dim3(16, 32), 256, 0, stream>>>(
            h, DMODEL, fc1t_p, DMODEL, fc1b + (size_t)l * FF,
            mid, FF, 1, nullptr, -1, 1, FF, DMODEL);
        gemm_bf16<2><<<dim3(32, 8), 256, 0, stream>>>(
            mid, FF, fc2t_p, FF, fc2b + (size_t)l * DMODEL,
            x, DMODEL, 0, x, DMODEL, 0, DMODEL, FF);
    }

    ln_kernel<<<MROWS, 256, 0, stream>>>(x, lnfg, lnfb, h);
    gemm_bf16<4><<<dim3(16, 393), 256, 0, stream>>>(
        h, DMODEL, lmwt, DMODEL, lmb,
        logits, VOCAB, 0, nullptr, -1, 0, VOCAB, DMODEL);

    loss1_kernel<<<MROWS, 256, 0, stream>>>(logits, tgt, nll);
    loss2_kernel<<<1, 256, 0, stream>>>(nll, lossp);
}

// Round 3
// 2881.118 us; speedup vs baseline: 2.5997x; 1.7817x over previous
//
#include <hip/hip_runtime.h>

#define T_SEQ 256
#define DMODEL 1024
#define NHEAD 16
#define HSZ 64
#define NLAYER 12
#define VOCAB 50257
#define FF 4096
#define MROWS 2048

using short8 = __attribute__((ext_vector_type(8))) short;
using f32x4  = __attribute__((ext_vector_type(4))) float;

__device__ __forceinline__ float bf2f(unsigned short u) {
    unsigned int x = ((unsigned int)u) << 16;
    return __builtin_bit_cast(float, x);
}
__device__ __forceinline__ unsigned short f2bf(float f) {
    unsigned int u = __builtin_bit_cast(unsigned int, f);
    unsigned int r = (u + 0x7fffu + ((u >> 16) & 1u)) >> 16;
    return (unsigned short)r;
}
__device__ __forceinline__ void async_copy16(const void* g, void* l) {
    __builtin_amdgcn_global_load_lds(
        (const __attribute__((address_space(1))) unsigned int*)g,
        (__attribute__((address_space(3))) unsigned int*)l, 16, 0, 0);
}

// ---------------------------------------------------------------------------
// Embedding
// ---------------------------------------------------------------------------
__global__ __launch_bounds__(256) void embed_kernel(
    const int* __restrict__ idx, const float* __restrict__ tok,
    const float* __restrict__ pos, float* __restrict__ x)
{
    int row = blockIdx.x, tid = threadIdx.x;
    int t = row & (T_SEQ - 1);
    int token = idx[row];
    float4 a = ((const float4*)(tok + (size_t)token * DMODEL))[tid];
    float4 p = ((const float4*)(pos + (size_t)t * DMODEL))[tid];
    float4 o;
    o.x = a.x + p.x; o.y = a.y + p.y; o.z = a.z + p.z; o.w = a.w + p.w;
    ((float4*)(x + (size_t)row * DMODEL))[tid] = o;
}

// ---------------------------------------------------------------------------
// LayerNorm: one block per row, bf16 output
// ---------------------------------------------------------------------------
__global__ __launch_bounds__(256) void ln_kernel(
    const float* __restrict__ x, const float* __restrict__ g,
    const float* __restrict__ b, unsigned short* __restrict__ out)
{
    int row = blockIdx.x, tid = threadIdx.x;
    float4 v = ((const float4*)(x + (size_t)row * DMODEL))[tid];
    float s  = v.x + v.y + v.z + v.w;
    float ss = v.x * v.x + v.y * v.y + v.z * v.z + v.w * v.w;
    for (int o = 32; o > 0; o >>= 1) {
        s  += __shfl_down(s, o);
        ss += __shfl_down(ss, o);
    }
    __shared__ float ps[4], pss[4];
    int wave = tid >> 6, lane = tid & 63;
    if (lane == 0) { ps[wave] = s; pss[wave] = ss; }
    __syncthreads();
    float st  = ps[0] + ps[1] + ps[2] + ps[3];
    float sst = pss[0] + pss[1] + pss[2] + pss[3];
    float mu  = st * (1.0f / DMODEL);
    float var = sst * (1.0f / DMODEL) - mu * mu;
    float rstd = rsqrtf(var + 1e-5f);
    float4 gv = ((const float4*)g)[tid];
    float4 bv = ((const float4*)b)[tid];
    ushort4 o4;
    o4.x = f2bf((v.x - mu) * rstd * gv.x + bv.x);
    o4.y = f2bf((v.y - mu) * rstd * gv.y + bv.y);
    o4.z = f2bf((v.z - mu) * rstd * gv.z + bv.z);
    o4.w = f2bf((v.w - mu) * rstd * gv.w + bv.w);
    ((ushort4*)out)[(size_t)row * (DMODEL / 4) + tid] = o4;
}

// ---------------------------------------------------------------------------
// Weight transpose: in [R,C] f32 (per layer) -> out [C,R] bf16 (per layer)
// ---------------------------------------------------------------------------
__global__ __launch_bounds__(256) void wtranspose_kernel(
    const float* __restrict__ in, unsigned short* __restrict__ out,
    int R, int C, long in_l, long out_l)
{
    int lyr = blockIdx.z;
    in  += (size_t)lyr * in_l;
    out += (size_t)lyr * out_l;
    __shared__ float tile[32][33];
    int tx = threadIdx.x & 31, ty = threadIdx.x >> 5;
    int c0 = blockIdx.x * 32, r0 = blockIdx.y * 32;
    #pragma unroll
    for (int i = 0; i < 4; i++) {
        int r = r0 + ty + i * 8, c = c0 + tx;
        tile[ty + i * 8][tx] = (c < C) ? in[(size_t)r * C + c] : 0.f;
    }
    __syncthreads();
    #pragma unroll
    for (int i = 0; i < 4; i++) {
        int c = c0 + ty + i * 8, r = r0 + tx;
        if (c < C) out[(size_t)c * R + r] = f2bf(tile[tx][ty + i * 8]);
    }
}

// ---------------------------------------------------------------------------
// QKV weight pack: Wq/Wk/Wv [H,D,HS] f32 -> out[n, d] bf16, n=seg*1024+h*64+s
// ---------------------------------------------------------------------------
__global__ __launch_bounds__(256) void qkvpack_kernel(
    const float* __restrict__ Wq, const float* __restrict__ Wk,
    const float* __restrict__ Wv, unsigned short* __restrict__ out,
    long w_l, long out_l)
{
    int z = blockIdx.z;
    int lyr = z / 48, r48 = z % 48;
    int seg = r48 >> 4, hh = r48 & 15;
    const float* W = (seg == 0 ? Wq : seg == 1 ? Wk : Wv)
                     + (size_t)lyr * w_l + (size_t)hh * DMODEL * HSZ;
    unsigned short* o = out + (size_t)lyr * out_l
                      + (size_t)(seg * 1024 + hh * 64) * DMODEL;
    __shared__ float tile[32][33];
    int tx = threadIdx.x & 31, ty = threadIdx.x >> 5;
    int d0 = blockIdx.x * 32, s0 = blockIdx.y * 32;
    #pragma unroll
    for (int i = 0; i < 4; i++)
        tile[ty + i * 8][tx] = W[(size_t)(d0 + ty + i * 8) * HSZ + s0 + tx];
    __syncthreads();
    #pragma unroll
    for (int i = 0; i < 4; i++)
        o[(size_t)(s0 + ty + i * 8) * DMODEL + d0 + tx] = f2bf(tile[tx][ty + i * 8]);
}

// ---------------------------------------------------------------------------
// bf16 MFMA GEMM: C[2048,N] = A[2048,K] @ Bt[N,K]^T, XCD-swizzled block map.
// If vtout != nullptr (QKV mode): cols >= 2048 (the V segment) are written
// transposed to vtout[b][h][s][t] (bf16) instead of C.
// ---------------------------------------------------------------------------
template<int MF>
__global__ __launch_bounds__(256) void gemm_bf16(
    const unsigned short* __restrict__ A, int lda,
    const unsigned short* __restrict__ Bt, int ldb,
    const float* __restrict__ bias,
    void* __restrict__ Cv, int ldc, int cbf16,
    const float* __restrict__ res, int ldr,
    int relu, int N, int K,
    unsigned short* __restrict__ vtout)
{
    constexpr int BM = MF * 32;
    __shared__ __align__(16) char As[BM * 128];
    __shared__ __align__(16) char Bs[128 * 128];
    int tid = threadIdx.x;
    int wave = tid >> 6, lane = tid & 63;
    int wr = wave >> 1, wc = wave & 1;
    // XCD-aware bijective remap (m204): flat%8 = XCD gets contiguous chunk
    int nwg = gridDim.x * gridDim.y;
    int flat = blockIdx.y * gridDim.x + blockIdx.x;
    int qch = nwg >> 3, rch = nwg & 7;
    int xcd = flat & 7, off = flat >> 3;
    int wg = (xcd < rch ? xcd * (qch + 1) : rch * (qch + 1) + (xcd - rch) * qch) + off;
    int m0 = (wg % gridDim.x) * BM, n0 = (wg / gridDim.x) * 128;

    f32x4 acc[MF][4];
    #pragma unroll
    for (int m = 0; m < MF; m++)
        #pragma unroll
        for (int n = 0; n < 4; n++)
            acc[m][n] = (f32x4){0.f, 0.f, 0.f, 0.f};

    int ksw = (((lane & 7) ^ (lane >> 3)) << 4);
    int KT = K >> 6;
    for (int kt = 0; kt < KT; kt++) {
        int k0 = kt << 6;
        __syncthreads();
        #pragma unroll
        for (int j = 0; j < MF; j++) {
            int row = (wave * MF + j) * 8 + (lane >> 3);
            const char* src = (const char*)A + ((size_t)(m0 + row) * lda + k0) * 2 + ksw;
            async_copy16(src, As + (wave * MF + j) * 1024);
        }
        #pragma unroll
        for (int j = 0; j < 4; j++) {
            int nrow = (wave * 4 + j) * 8 + (lane >> 3);
            const char* src = (const char*)Bt + ((size_t)(n0 + nrow) * ldb + k0) * 2 + ksw;
            async_copy16(src, Bs + (wave * 4 + j) * 1024);
        }
        __syncthreads();
        #pragma unroll
        for (int ks = 0; ks < 2; ks++) {
            int kb = ks * 64 + ((lane >> 4) << 4);
            short8 a[MF], b[4];
            #pragma unroll
            for (int m = 0; m < MF; m++) {
                int r = wr * (MF * 16) + m * 16 + (lane & 15);
                a[m] = *(const short8*)(const void*)(As + r * 128 + (kb ^ ((r & 7) << 4)));
            }
            #pragma unroll
            for (int n = 0; n < 4; n++) {
                int c = wc * 64 + n * 16 + (lane & 15);
                b[n] = *(const short8*)(const void*)(Bs + c * 128 + (kb ^ ((c & 7) << 4)));
            }
            #pragma unroll
            for (int m = 0; m < MF; m++)
                #pragma unroll
                for (int n = 0; n < 4; n++)
                    acc[m][n] = __builtin_amdgcn_mfma_f32_16x16x32_bf16(a[m], b[n], acc[m][n], 0, 0, 0);
        }
    }
    #pragma unroll
    for (int m = 0; m < MF; m++) {
        int rowb = m0 + wr * (MF * 16) + m * 16 + ((lane >> 4) << 2);
        #pragma unroll
        for (int n = 0; n < 4; n++) {
            int col = n0 + wc * 64 + n * 16 + (lane & 15);
            if (col < N) {
                float bi = bias ? bias[col] : 0.f;
                #pragma unroll
                for (int r2 = 0; r2 < 4; r2++) {
                    float v = acc[m][n][r2] + bi;
                    if (relu) v = fmaxf(v, 0.f);
                    int row = rowb + r2;
                    if (ldr >= 0) v += res[(size_t)row * ldr + col];
                    if (vtout && col >= 2048) {
                        int hh = (col - 2048) >> 6, sdim = (col - 2048) & 63;
                        int bb = row >> 8, tt = row & 255;
                        vtout[((((size_t)bb * NHEAD + hh) * HSZ + sdim) * T_SEQ) + tt] = f2bf(v);
                    } else if (cbf16) {
                        ((unsigned short*)Cv)[(size_t)row * ldc + col] = f2bf(v);
                    } else {
                        ((float*)Cv)[(size_t)row * ldc + col] = v;
                    }
                }
            }
        }
    }
}

// ---------------------------------------------------------------------------
// Fused flash attention (MFMA). Grid (4 qtiles, 16 h, 8 b), 4 waves.
// Wave w owns q-rows qt*64 + w*16 .. +15. K tiles of 64 streamed via LDS.
// Swapped QK^T: S^T[u,q] = mfma(A=K_frag, B=Q_frag) -> q is lane-local.
// P bounced through wave-private swizzled LDS to become the PV A-operand.
// V consumed from vt[b][h][s][t] (pre-transposed by the QKV GEMM epilogue).
// ---------------------------------------------------------------------------
__global__ __launch_bounds__(256) void attn_fused_kernel(
    const unsigned short* __restrict__ qkv, const unsigned short* __restrict__ vt,
    float* __restrict__ x)
{
    int qt = blockIdx.x, hh = blockIdx.y, b = blockIdx.z;
    int tid = threadIdx.x;
    int wave = tid >> 6, lane = tid & 63;
    int g = lane >> 4, q = lane & 15;

    __shared__ __align__(16) char Kb[2][8192];   // [64 u][128 B], XOR-swizzled
    __shared__ __align__(16) char Vb[2][8192];   // [64 s][128 B], XOR-swizzled
    __shared__ __align__(16) char Plds[4][2048]; // per-wave [16 q][128 B]

    // Q fragments (B-operand): col=q=lane&15, k=d=(g*8..+7)+32*ks
    int qrow = b * T_SEQ + qt * 64 + wave * 16 + q;
    const char* qp = (const char*)qkv + ((size_t)qrow * 3072 + hh * HSZ) * 2;
    short8 qreg[2];
    qreg[0] = *(const short8*)(const void*)(qp + (g << 4));
    qreg[1] = *(const short8*)(const void*)(qp + 64 + (g << 4));

    char* Pw = Plds[wave];

    f32x4 oacc[4];
    #pragma unroll
    for (int f = 0; f < 4; f++) oacc[f] = (f32x4){0.f, 0.f, 0.f, 0.f};
    float m_run = -1e30f, l_run = 0.f;

    int srow = wave * 8 + (lane >> 3);          // staging row within 32-row pass
    int sbyte = ((lane & 7) << 4) ^ ((srow & 7) << 4);

    // stage ktile kt into buffer bi
    auto stage = [&](int kt, int bi) {
        #pragma unroll
        for (int c = 0; c < 2; c++) {
            int row = c * 32 + srow;
            const char* src = (const char*)qkv +
                ((size_t)(b * T_SEQ + kt * 64 + row) * 3072 + 1024 + hh * HSZ) * 2 + sbyte;
            async_copy16(src, Kb[bi] + c * 4096 + wave * 1024);
        }
        #pragma unroll
        for (int c = 0; c < 2; c++) {
            int row = c * 32 + srow;
            const char* src = (const char*)vt +
                (((size_t)(b * NHEAD + hh) * HSZ + row) * T_SEQ + kt * 64) * 2 + sbyte;
            async_copy16(src, Vb[bi] + c * 4096 + wave * 1024);
        }
    };

    stage(0, 0);
    for (int kt = 0; kt <= qt; kt++) {
        int bi = kt & 1;
        __syncthreads();                  // staged tile ready (vmcnt drained)
        if (kt < qt) stage(kt + 1, bi ^ 1);

        // ---- S^T = K Q^T ----
        f32x4 sacc[4];
        #pragma unroll
        for (int f = 0; f < 4; f++) sacc[f] = (f32x4){0.f, 0.f, 0.f, 0.f};
        #pragma unroll
        for (int ks = 0; ks < 2; ks++) {
            int kb = ks * 64 + (g << 4);
            #pragma unroll
            for (int f = 0; f < 4; f++) {
                int u = f * 16 + q;
                short8 kf = *(const short8*)(const void*)(Kb[bi] + u * 128 + (kb ^ ((u & 7) << 4)));
                sacc[f] = __builtin_amdgcn_mfma_f32_16x16x32_bf16(kf, qreg[ks], sacc[f], 0, 0, 0);
            }
        }
        // ---- softmax (q lane-local; u spread over 16 regs x 4 groups) ----
        float sv[4][4];
        #pragma unroll
        for (int f = 0; f < 4; f++)
            #pragma unroll
            for (int r = 0; r < 4; r++) {
                float v = sacc[f][r] * 0.125f;
                if (kt == qt) {
                    int u_loc = f * 16 + g * 4 + r;
                    if (u_loc > wave * 16 + q) v = -1e30f;
                }
                sv[f][r] = v;
            }
        float pm = -1e30f;
        #pragma unroll
        for (int f = 0; f < 4; f++)
            #pragma unroll
            for (int r = 0; r < 4; r++) pm = fmaxf(pm, sv[f][r]);
        pm = fmaxf(pm, __shfl_xor(pm, 16));
        pm = fmaxf(pm, __shfl_xor(pm, 32));
        float mnew = fmaxf(m_run, pm);
        float corr = __expf(m_run - mnew);
        float p[4][4];
        float ls = 0.f;
        #pragma unroll
        for (int f = 0; f < 4; f++)
            #pragma unroll
            for (int r = 0; r < 4; r++) {
                p[f][r] = __expf(sv[f][r] - mnew);
                ls += p[f][r];
            }
        ls += __shfl_xor(ls, 16);
        ls += __shfl_xor(ls, 32);
        l_run = l_run * corr + ls;
        m_run = mnew;
        // ---- rescale O (rows q' = g*4+r; corr lives at lanes with lane&15==q') ----
        #pragma unroll
        for (int r = 0; r < 4; r++) {
            float cr = __shfl(corr, (lane & 48) | (g * 4 + r));
            #pragma unroll
            for (int f = 0; f < 4; f++) oacc[f][r] *= cr;
        }
        // ---- pack P -> wave-private LDS [q][u] (swizzled) ----
        #pragma unroll
        for (int f = 0; f < 4; f++)
            #pragma unroll
            for (int rp = 0; rp < 2; rp++) {
                int ue = f * 16 + g * 4 + rp * 2;
                unsigned int pk = (unsigned int)f2bf(p[f][rp * 2])
                                | ((unsigned int)f2bf(p[f][rp * 2 + 1]) << 16);
                *(unsigned int*)(void*)(Pw + q * 128 + ((ue * 2) ^ ((q & 7) << 4))) = pk;
            }
        // ---- PV: O[q,s] += P[q,u] V[u,s] ----
        #pragma unroll
        for (int ks = 0; ks < 2; ks++) {
            int kb = ks * 64 + (g << 4);
            short8 pa = *(const short8*)(const void*)(Pw + q * 128 + (kb ^ ((q & 7) << 4)));
            #pragma unroll
            for (int f = 0; f < 4; f++) {
                int s = f * 16 + q;
                short8 vf = *(const short8*)(const void*)(Vb[bi] + s * 128 + (kb ^ ((s & 7) << 4)));
                oacc[f] = __builtin_amdgcn_mfma_f32_16x16x32_bf16(pa, vf, oacc[f], 0, 0, 0);
            }
        }
    }
    // ---- epilogue: O /= l, residual-add into x ----
    float inv = 1.0f / l_run;
    #pragma unroll
    for (int r = 0; r < 4; r++) {
        float ir = __shfl(inv, (lane & 48) | (g * 4 + r));
        int row_g = b * T_SEQ + qt * 64 + wave * 16 + g * 4 + r;
        #pragma unroll
        for (int f = 0; f < 4; f++) {
            size_t xi = (size_t)row_g * DMODEL + hh * HSZ + f * 16 + q;
            x[xi] += oacc[f][r] * ir;
        }
    }
}

// ---------------------------------------------------------------------------
// Loss pass 1: per-row online logsumexp -> nll[row]
// ---------------------------------------------------------------------------
__global__ __launch_bounds__(256) void loss1_kernel(
    const float* __restrict__ logits, const int* __restrict__ targets,
    float* __restrict__ nll)
{
    int r = blockIdx.x, tid = threadIdx.x;
    const float* row = logits + (size_t)r * VOCAB;
    float m = -3.4e38f, s = 0.f;
    for (int v = tid; v < VOCAB; v += 256) {
        float xv = row[v];
        float nm = fmaxf(m, xv);
        s = s * __expf(m - nm) + __expf(xv - nm);
        m = nm;
    }
    __shared__ float ms[256], ssh[256];
    ms[tid] = m; ssh[tid] = s;
    __syncthreads();
    for (int o = 128; o > 0; o >>= 1) {
        if (tid < o) {
            float m1 = ms[tid], s1 = ssh[tid];
            float m2 = ms[tid + o], s2 = ssh[tid + o];
            float nm = fmaxf(m1, m2);
            ssh[tid] = s1 * __expf(m1 - nm) + s2 * __expf(m2 - nm);
            ms[tid] = nm;
        }
        __syncthreads();
    }
    if (tid == 0) nll[r] = logf(ssh[0]) + ms[0] - row[targets[r]];
}

__global__ __launch_bounds__(256) void loss2_kernel(
    const float* __restrict__ nll, float* __restrict__ out)
{
    int tid = threadIdx.x;
    float s = 0.f;
    for (int i = tid; i < MROWS; i += 256) s += nll[i];
    __shared__ float red[256];
    red[tid] = s;
    __syncthreads();
    for (int o = 128; o > 0; o >>= 1) {
        if (tid < o) red[tid] += red[tid + o];
        __syncthreads();
    }
    if (tid == 0) out[0] = red[0] * (1.0f / MROWS);
}

// ---------------------------------------------------------------------------
extern "C" void kernel_launch(void* const* d_in, const int* in_sizes, int n_in,
                              void* d_out, int out_size, void* d_ws, size_t ws_size,
                              hipStream_t stream)
{
    const int*   idx  = (const int*)d_in[0];
    const int*   tgt  = (const int*)d_in[1];
    const float* tok  = (const float*)d_in[2];
    const float* pos  = (const float*)d_in[3];
    const float* Wq   = (const float*)d_in[4];
    const float* Wk   = (const float*)d_in[5];
    const float* Wv   = (const float*)d_in[6];
    const float* ln1g = (const float*)d_in[7];
    const float* ln1b = (const float*)d_in[8];
    const float* ln2g = (const float*)d_in[9];
    const float* ln2b = (const float*)d_in[10];
    const float* fc1w = (const float*)d_in[11];
    const float* fc1b = (const float*)d_in[12];
    const float* fc2w = (const float*)d_in[13];
    const float* fc2b = (const float*)d_in[14];
    const float* lnfg = (const float*)d_in[15];
    const float* lnfb = (const float*)d_in[16];
    const float* lmw  = (const float*)d_in[17];
    const float* lmb  = (const float*)d_in[18];

    char* ws = (char*)d_ws;
    float*          x    = (float*)(ws + 0);                  // 8.39 MB
    unsigned short* h    = (unsigned short*)(ws + 8388608);   // 4.19 MB
    unsigned short* qkv  = (unsigned short*)(ws + 12582912);  // 12.58 MB
    unsigned short* vt   = (unsigned short*)(ws + 25165824);  // 4.19 MB [b][h][s][t]
    unsigned short* mid  = (unsigned short*)(ws + 29360128);  // 16.78 MB
    float*          nll  = (float*)(ws + 46137344);           // 8 KB
    unsigned short* lmwt = (unsigned short*)(ws + 46145536);  // 103.02 MB
    // end lmwt: 149168128
    const size_t UP_NEED = 425992192ull;
    bool upfront = (ws_size >= UP_NEED);
    unsigned short* qkvt = (unsigned short*)(ws + 149168128);
    unsigned short* fc1t, * fc2t;
    long qkvt_l, fc1t_l, fc2t_l;
    if (upfront) {
        fc1t = (unsigned short*)(ws + 224665600);
        fc2t = (unsigned short*)(ws + 325328896);
        qkvt_l = 3072 * 1024; fc1t_l = (long)FF * 1024; fc2t_l = (long)1024 * FF;
    } else {
        fc1t = (unsigned short*)(ws + 155459584);
        fc2t = (unsigned short*)(ws + 163848192);
        qkvt_l = 0; fc1t_l = 0; fc2t_l = 0;
    }
    float* logits = (float*)d_out;
    float* lossp  = logits + (size_t)MROWS * VOCAB;

    const long WQKV_L = (long)NHEAD * DMODEL * HSZ;
    if (upfront) {
        qkvpack_kernel<<<dim3(32, 2, 48 * NLAYER), 256, 0, stream>>>(
            Wq, Wk, Wv, qkvt, WQKV_L, qkvt_l);
        wtranspose_kernel<<<dim3(128, 32, NLAYER), 256, 0, stream>>>(
            fc1w, fc1t, DMODEL, FF, (long)DMODEL * FF, fc1t_l);
        wtranspose_kernel<<<dim3(32, 128, NLAYER), 256, 0, stream>>>(
            fc2w, fc2t, FF, DMODEL, (long)FF * DMODEL, fc2t_l);
    }
    wtranspose_kernel<<<dim3(1571, 32, 1), 256, 0, stream>>>(
        lmw, lmwt, DMODEL, VOCAB, 0, 0);

    embed_kernel<<<MROWS, 256, 0, stream>>>(idx, tok, pos, x);

    for (int l = 0; l < NLAYER; l++) {
        unsigned short* qkvt_p = qkvt + (size_t)l * qkvt_l;
        unsigned short* fc1t_p = fc1t + (size_t)l * fc1t_l;
        unsigned short* fc2t_p = fc2t + (size_t)l * fc2t_l;
        if (!upfront) {
            qkvpack_kernel<<<dim3(32, 2, 48), 256, 0, stream>>>(
                Wq + (size_t)l * WQKV_L, Wk + (size_t)l * WQKV_L,
                Wv + (size_t)l * WQKV_L, qkvt, WQKV_L, 0);
            wtranspose_kernel<<<dim3(128, 32, 1), 256, 0, stream>>>(
                fc1w + (size_t)l * DMODEL * FF, fc1t, DMODEL, FF, 0, 0);
            wtranspose_kernel<<<dim3(32, 128, 1), 256, 0, stream>>>(
                fc2w + (size_t)l * FF * DMODEL, fc2t, FF, DMODEL, 0, 0);
        }
        ln_kernel<<<MROWS, 256, 0, stream>>>(x, ln1g + l * DMODEL, ln1b + l * DMODEL, h);
        gemm_bf16<4><<<dim3(16, 24), 256, 0, stream>>>(
            h, DMODEL, qkvt_p, DMODEL, nullptr,
            qkv, 3072, 1, nullptr, -1, 0, 3072, DMODEL, vt);
        attn_fused_kernel<<<dim3(4, NHEAD, 8), 256, 0, stream>>>(qkv, vt, x);
        ln_kernel<<<MROWS, 256, 0, stream>>>(x, ln2g + l * DMODEL, ln2b + l * DMODEL, h);
        gemm_bf16<4><<<dim3(16, 32), 256, 0, stream>>>(
            h, DMODEL, fc1t_p, DMODEL, fc1b + (size_t)l * FF,
            mid, FF, 1, nullptr, -1, 1, FF, DMODEL, nullptr);
        gemm_bf16<2><<<dim3(32, 8), 256, 0, stream>>>(
            mid, FF, fc2t_p, FF, fc2b + (size_t)l * DMODEL,
            x, DMODEL, 0, x, DMODEL, 0, DMODEL, FF, nullptr);
    }

    ln_kernel<<<MROWS, 256, 0, stream>>>(x, lnfg, lnfb, h);
    gemm_bf16<4><<<dim3(16, 393), 256, 0, stream>>>(
        h, DMODEL, lmwt, DMODEL, lmb,
        logits, VOCAB, 0, nullptr, -1, 0, VOCAB, DMODEL, nullptr);

    loss1_kernel<<<MROWS, 256, 0, stream>>>(logits, tgt, nll);
    loss2_kernel<<<1, 256, 0, stream>>>(nll, lossp);
}

// Round 4
// 2482.545 us; speedup vs baseline: 3.0170x; 1.1605x over previous
//
#include <hip/hip_runtime.h>

#define T_SEQ 256
#define DMODEL 1024
#define NHEAD 16
#define HSZ 64
#define NLAYER 12
#define VOCAB 50257
#define NPAD 50304
#define FF 4096
#define MROWS 2048
#define NSTRIPS 786

using short8 = __attribute__((ext_vector_type(8))) short;
using f32x4  = __attribute__((ext_vector_type(4))) float;

__device__ __forceinline__ float bf2f(unsigned short u) {
    unsigned int x = ((unsigned int)u) << 16;
    return __builtin_bit_cast(float, x);
}
__device__ __forceinline__ unsigned short f2bf(float f) {
    unsigned int u = __builtin_bit_cast(unsigned int, f);
    unsigned int r = (u + 0x7fffu + ((u >> 16) & 1u)) >> 16;
    return (unsigned short)r;
}
__device__ __forceinline__ void async_copy16(const void* g, void* l) {
    __builtin_amdgcn_global_load_lds(
        (const __attribute__((address_space(1))) unsigned int*)g,
        (__attribute__((address_space(3))) unsigned int*)l, 16, 0, 0);
}

// ---------------------------------------------------------------------------
// Embedding
// ---------------------------------------------------------------------------
__global__ __launch_bounds__(256) void embed_kernel(
    const int* __restrict__ idx, const float* __restrict__ tok,
    const float* __restrict__ pos, float* __restrict__ x)
{
    int row = blockIdx.x, tid = threadIdx.x;
    int t = row & (T_SEQ - 1);
    int token = idx[row];
    float4 a = ((const float4*)(tok + (size_t)token * DMODEL))[tid];
    float4 p = ((const float4*)(pos + (size_t)t * DMODEL))[tid];
    float4 o;
    o.x = a.x + p.x; o.y = a.y + p.y; o.z = a.z + p.z; o.w = a.w + p.w;
    ((float4*)(x + (size_t)row * DMODEL))[tid] = o;
}

// ---------------------------------------------------------------------------
// LayerNorm: one block per row, bf16 output
// ---------------------------------------------------------------------------
__global__ __launch_bounds__(256) void ln_kernel(
    const float* __restrict__ x, const float* __restrict__ g,
    const float* __restrict__ b, unsigned short* __restrict__ out)
{
    int row = blockIdx.x, tid = threadIdx.x;
    float4 v = ((const float4*)(x + (size_t)row * DMODEL))[tid];
    float s  = v.x + v.y + v.z + v.w;
    float ss = v.x * v.x + v.y * v.y + v.z * v.z + v.w * v.w;
    for (int o = 32; o > 0; o >>= 1) {
        s  += __shfl_down(s, o);
        ss += __shfl_down(ss, o);
    }
    __shared__ float ps[4], pss[4];
    int wave = tid >> 6, lane = tid & 63;
    if (lane == 0) { ps[wave] = s; pss[wave] = ss; }
    __syncthreads();
    float st  = ps[0] + ps[1] + ps[2] + ps[3];
    float sst = pss[0] + pss[1] + pss[2] + pss[3];
    float mu  = st * (1.0f / DMODEL);
    float var = sst * (1.0f / DMODEL) - mu * mu;
    float rstd = rsqrtf(var + 1e-5f);
    float4 gv = ((const float4*)g)[tid];
    float4 bv = ((const float4*)b)[tid];
    ushort4 o4;
    o4.x = f2bf((v.x - mu) * rstd * gv.x + bv.x);
    o4.y = f2bf((v.y - mu) * rstd * gv.y + bv.y);
    o4.z = f2bf((v.z - mu) * rstd * gv.z + bv.z);
    o4.w = f2bf((v.w - mu) * rstd * gv.w + bv.w);
    ((ushort4*)out)[(size_t)row * (DMODEL / 4) + tid] = o4;
}

// ---------------------------------------------------------------------------
// Weight transpose: in [R,C] f32 -> out [C,R] bf16; cols [C, Cout) zero-filled
// ---------------------------------------------------------------------------
__global__ __launch_bounds__(256) void wtranspose_kernel(
    const float* __restrict__ in, unsigned short* __restrict__ out,
    int R, int C, int Cout, long in_l, long out_l)
{
    int lyr = blockIdx.z;
    in  += (size_t)lyr * in_l;
    out += (size_t)lyr * out_l;
    __shared__ float tile[32][33];
    int tx = threadIdx.x & 31, ty = threadIdx.x >> 5;
    int c0 = blockIdx.x * 32, r0 = blockIdx.y * 32;
    #pragma unroll
    for (int i = 0; i < 4; i++) {
        int r = r0 + ty + i * 8, c = c0 + tx;
        tile[ty + i * 8][tx] = (c < C) ? in[(size_t)r * C + c] : 0.f;
    }
    __syncthreads();
    #pragma unroll
    for (int i = 0; i < 4; i++) {
        int c = c0 + ty + i * 8, r = r0 + tx;
        if (c < Cout) out[(size_t)c * R + r] = f2bf(tile[tx][ty + i * 8]);
    }
}

// ---------------------------------------------------------------------------
// QKV weight pack: Wq/Wk/Wv [H,D,HS] f32 -> out[n, d] bf16, n=seg*1024+h*64+s
// ---------------------------------------------------------------------------
__global__ __launch_bounds__(256) void qkvpack_kernel(
    const float* __restrict__ Wq, const float* __restrict__ Wk,
    const float* __restrict__ Wv, unsigned short* __restrict__ out,
    long w_l, long out_l)
{
    int z = blockIdx.z;
    int lyr = z / 48, r48 = z % 48;
    int seg = r48 >> 4, hh = r48 & 15;
    const float* W = (seg == 0 ? Wq : seg == 1 ? Wk : Wv)
                     + (size_t)lyr * w_l + (size_t)hh * DMODEL * HSZ;
    unsigned short* o = out + (size_t)lyr * out_l
                      + (size_t)(seg * 1024 + hh * 64) * DMODEL;
    __shared__ float tile[32][33];
    int tx = threadIdx.x & 31, ty = threadIdx.x >> 5;
    int d0 = blockIdx.x * 32, s0 = blockIdx.y * 32;
    #pragma unroll
    for (int i = 0; i < 4; i++)
        tile[ty + i * 8][tx] = W[(size_t)(d0 + ty + i * 8) * HSZ + s0 + tx];
    __syncthreads();
    #pragma unroll
    for (int i = 0; i < 4; i++)
        o[(size_t)(s0 + ty + i * 8) * DMODEL + d0 + tx] = f2bf(tile[tx][ty + i * 8]);
}

// ---------------------------------------------------------------------------
// Shared bf16 MFMA GEMM core: C[2048,N] = A[2048,K] @ Bt[N,K]^T.
// 128-col tile, BM = MF*32, BK=64, 4 waves, 16x16x32 MFMA, XOR-swizzled LDS,
// both operands staged via global_load_lds (pre-swizzled source).
// ---------------------------------------------------------------------------
template<int MF, bool QKV, bool RELU, bool RES, bool CBF16, bool LOSSP>
__device__ __forceinline__ void gemm_core(
    const unsigned short* __restrict__ A, int lda,
    const unsigned short* __restrict__ Bt, int ldb,
    const float* __restrict__ bias,
    void* __restrict__ Cv, int ldc,
    const float* __restrict__ res, int ldr,
    int N, int K,
    unsigned short* __restrict__ vtout,
    float* __restrict__ pmax, float* __restrict__ psum)
{
    constexpr int BM = MF * 32;
    __shared__ __align__(16) char As[BM * 128];
    __shared__ __align__(16) char Bs[128 * 128];
    int tid = threadIdx.x;
    int wave = tid >> 6, lane = tid & 63;
    int wr = wave >> 1, wc = wave & 1;
    int m0 = blockIdx.x * BM, n0 = blockIdx.y * 128;

    f32x4 acc[MF][4];
    #pragma unroll
    for (int m = 0; m < MF; m++)
        #pragma unroll
        for (int n = 0; n < 4; n++)
            acc[m][n] = (f32x4){0.f, 0.f, 0.f, 0.f};

    int ksw = (((lane & 7) ^ (lane >> 3)) << 4);
    int KT = K >> 6;
    for (int kt = 0; kt < KT; kt++) {
        int k0 = kt << 6;
        __syncthreads();
        #pragma unroll
        for (int j = 0; j < MF; j++) {
            int row = (wave * MF + j) * 8 + (lane >> 3);
            const char* src = (const char*)A + ((size_t)(m0 + row) * lda + k0) * 2 + ksw;
            async_copy16(src, As + (wave * MF + j) * 1024);
        }
        #pragma unroll
        for (int j = 0; j < 4; j++) {
            int nrow = (wave * 4 + j) * 8 + (lane >> 3);
            const char* src = (const char*)Bt + ((size_t)(n0 + nrow) * ldb + k0) * 2 + ksw;
            async_copy16(src, Bs + (wave * 4 + j) * 1024);
        }
        __syncthreads();
        #pragma unroll
        for (int ks = 0; ks < 2; ks++) {
            int kb = ks * 64 + ((lane >> 4) << 4);
            short8 a[MF], b[4];
            #pragma unroll
            for (int m = 0; m < MF; m++) {
                int r = wr * (MF * 16) + m * 16 + (lane & 15);
                a[m] = *(const short8*)(const void*)(As + r * 128 + (kb ^ ((r & 7) << 4)));
            }
            #pragma unroll
            for (int n = 0; n < 4; n++) {
                int c = wc * 64 + n * 16 + (lane & 15);
                b[n] = *(const short8*)(const void*)(Bs + c * 128 + (kb ^ ((c & 7) << 4)));
            }
            #pragma unroll
            for (int m = 0; m < MF; m++)
                #pragma unroll
                for (int n = 0; n < 4; n++)
                    acc[m][n] = __builtin_amdgcn_mfma_f32_16x16x32_bf16(a[m], b[n], acc[m][n], 0, 0, 0);
        }
    }
    #pragma unroll
    for (int m = 0; m < MF; m++) {
        int rowb = m0 + wr * (MF * 16) + m * 16 + ((lane >> 4) << 2);
        float mx[4], se[4];
        if (LOSSP) {
            #pragma unroll
            for (int r2 = 0; r2 < 4; r2++) { mx[r2] = -1e30f; se[r2] = 0.f; }
        }
        #pragma unroll
        for (int n = 0; n < 4; n++) {
            int col = n0 + wc * 64 + n * 16 + (lane & 15);
            if (col < N) {
                float bi = bias ? bias[col] : 0.f;
                #pragma unroll
                for (int r2 = 0; r2 < 4; r2++) {
                    float v = acc[m][n][r2] + bi;
                    if (RELU) v = fmaxf(v, 0.f);
                    int row = rowb + r2;
                    if (RES) v += res[(size_t)row * ldr + col];
                    if (QKV && col >= 2048) {
                        int hh = (col - 2048) >> 6, sdim = (col - 2048) & 63;
                        int bb = row >> 8, tt = row & 255;
                        vtout[((((size_t)bb * NHEAD + hh) * HSZ + sdim) * T_SEQ) + tt] = f2bf(v);
                    } else if (CBF16) {
                        ((unsigned short*)Cv)[(size_t)row * ldc + col] = f2bf(v);
                    } else {
                        ((float*)Cv)[(size_t)row * ldc + col] = v;
                    }
                    if (LOSSP) {
                        float nm = fmaxf(mx[r2], v);
                        se[r2] = se[r2] * __expf(mx[r2] - nm) + __expf(v - nm);
                        mx[r2] = nm;
                    }
                }
            }
        }
        if (LOSSP) {
            #pragma unroll
            for (int r2 = 0; r2 < 4; r2++) {
                float M = mx[r2], S = se[r2];
                #pragma unroll
                for (int o = 1; o < 16; o <<= 1) {
                    float M2 = __shfl_xor(M, o), S2 = __shfl_xor(S, o);
                    float nm = fmaxf(M, M2);
                    S = S * __expf(M - nm) + S2 * __expf(M2 - nm);
                    M = nm;
                }
                if ((lane & 15) == 0) {
                    int row = rowb + r2;
                    int strip = blockIdx.y * 2 + wc;
                    pmax[(size_t)row * NSTRIPS + strip] = M;
                    psum[(size_t)row * NSTRIPS + strip] = S;
                }
            }
        }
    }
}

__global__ __launch_bounds__(256) void gemm_qkv(
    const unsigned short* __restrict__ A, const unsigned short* __restrict__ Bt,
    unsigned short* __restrict__ C, unsigned short* __restrict__ vtout)
{
    gemm_core<4, true, false, false, true, false>(
        A, DMODEL, Bt, DMODEL, nullptr, C, 3072, nullptr, 0, 3072, DMODEL,
        vtout, nullptr, nullptr);
}

__global__ __launch_bounds__(256) void gemm_fc1(
    const unsigned short* __restrict__ A, const unsigned short* __restrict__ Bt,
    const float* __restrict__ bias, unsigned short* __restrict__ C)
{
    gemm_core<4, false, true, false, true, false>(
        A, DMODEL, Bt, DMODEL, bias, C, FF, nullptr, 0, FF, DMODEL,
        nullptr, nullptr, nullptr);
}

__global__ __launch_bounds__(256) void gemm_fc2(
    const unsigned short* __restrict__ A, const unsigned short* __restrict__ Bt,
    const float* __restrict__ bias, float* __restrict__ C,
    const float* __restrict__ res)
{
    gemm_core<2, false, false, true, false, false>(
        A, FF, Bt, FF, bias, C, DMODEL, res, DMODEL, DMODEL, FF,
        nullptr, nullptr, nullptr);
}

__global__ __launch_bounds__(256) void gemm_lm(
    const unsigned short* __restrict__ A, const unsigned short* __restrict__ Bt,
    const float* __restrict__ bias, float* __restrict__ C,
    float* __restrict__ pmax, float* __restrict__ psum)
{
    gemm_core<4, false, false, false, false, true>(
        A, DMODEL, Bt, DMODEL, bias, C, VOCAB, nullptr, 0, VOCAB, DMODEL,
        nullptr, pmax, psum);
}

// ---------------------------------------------------------------------------
// Fused flash attention (MFMA). Grid (4 qtiles, 16 h, 8 b), 4 waves.
// ---------------------------------------------------------------------------
__global__ __launch_bounds__(256) void attn_fused_kernel(
    const unsigned short* __restrict__ qkv, const unsigned short* __restrict__ vt,
    float* __restrict__ x)
{
    int qt = blockIdx.x, hh = blockIdx.y, b = blockIdx.z;
    int tid = threadIdx.x;
    int wave = tid >> 6, lane = tid & 63;
    int g = lane >> 4, q = lane & 15;

    __shared__ __align__(16) char Kb[2][8192];
    __shared__ __align__(16) char Vb[2][8192];
    __shared__ __align__(16) char Plds[4][2048];

    int qrow = b * T_SEQ + qt * 64 + wave * 16 + q;
    const char* qp = (const char*)qkv + ((size_t)qrow * 3072 + hh * HSZ) * 2;
    short8 qreg[2];
    qreg[0] = *(const short8*)(const void*)(qp + (g << 4));
    qreg[1] = *(const short8*)(const void*)(qp + 64 + (g << 4));

    char* Pw = Plds[wave];

    f32x4 oacc[4];
    #pragma unroll
    for (int f = 0; f < 4; f++) oacc[f] = (f32x4){0.f, 0.f, 0.f, 0.f};
    float m_run = -1e30f, l_run = 0.f;

    int srow = wave * 8 + (lane >> 3);
    int sbyte = ((lane & 7) << 4) ^ ((srow & 7) << 4);

    auto stage = [&](int kt, int bi) {
        #pragma unroll
        for (int c = 0; c < 2; c++) {
            int row = c * 32 + srow;
            const char* src = (const char*)qkv +
                ((size_t)(b * T_SEQ + kt * 64 + row) * 3072 + 1024 + hh * HSZ) * 2 + sbyte;
            async_copy16(src, Kb[bi] + c * 4096 + wave * 1024);
        }
        #pragma unroll
        for (int c = 0; c < 2; c++) {
            int row = c * 32 + srow;
            const char* src = (const char*)vt +
                (((size_t)(b * NHEAD + hh) * HSZ + row) * T_SEQ + kt * 64) * 2 + sbyte;
            async_copy16(src, Vb[bi] + c * 4096 + wave * 1024);
        }
    };

    stage(0, 0);
    for (int kt = 0; kt <= qt; kt++) {
        int bi = kt & 1;
        __syncthreads();
        if (kt < qt) stage(kt + 1, bi ^ 1);

        f32x4 sacc[4];
        #pragma unroll
        for (int f = 0; f < 4; f++) sacc[f] = (f32x4){0.f, 0.f, 0.f, 0.f};
        #pragma unroll
        for (int ks = 0; ks < 2; ks++) {
            int kb = ks * 64 + (g << 4);
            #pragma unroll
            for (int f = 0; f < 4; f++) {
                int u = f * 16 + q;
                short8 kf = *(const short8*)(const void*)(Kb[bi] + u * 128 + (kb ^ ((u & 7) << 4)));
                sacc[f] = __builtin_amdgcn_mfma_f32_16x16x32_bf16(kf, qreg[ks], sacc[f], 0, 0, 0);
            }
        }
        float sv[4][4];
        #pragma unroll
        for (int f = 0; f < 4; f++)
            #pragma unroll
            for (int r = 0; r < 4; r++) {
                float v = sacc[f][r] * 0.125f;
                if (kt == qt) {
                    int u_loc = f * 16 + g * 4 + r;
                    if (u_loc > wave * 16 + q) v = -1e30f;
                }
                sv[f][r] = v;
            }
        float pm = -1e30f;
        #pragma unroll
        for (int f = 0; f < 4; f++)
            #pragma unroll
            for (int r = 0; r < 4; r++) pm = fmaxf(pm, sv[f][r]);
        pm = fmaxf(pm, __shfl_xor(pm, 16));
        pm = fmaxf(pm, __shfl_xor(pm, 32));
        float mnew = fmaxf(m_run, pm);
        float corr = __expf(m_run - mnew);
        float p[4][4];
        float ls = 0.f;
        #pragma unroll
        for (int f = 0; f < 4; f++)
            #pragma unroll
            for (int r = 0; r < 4; r++) {
                p[f][r] = __expf(sv[f][r] - mnew);
                ls += p[f][r];
            }
        ls += __shfl_xor(ls, 16);
        ls += __shfl_xor(ls, 32);
        l_run = l_run * corr + ls;
        m_run = mnew;
        #pragma unroll
        for (int r = 0; r < 4; r++) {
            float cr = __shfl(corr, (lane & 48) | (g * 4 + r));
            #pragma unroll
            for (int f = 0; f < 4; f++) oacc[f][r] *= cr;
        }
        #pragma unroll
        for (int f = 0; f < 4; f++)
            #pragma unroll
            for (int rp = 0; rp < 2; rp++) {
                int ue = f * 16 + g * 4 + rp * 2;
                unsigned int pk = (unsigned int)f2bf(p[f][rp * 2])
                                | ((unsigned int)f2bf(p[f][rp * 2 + 1]) << 16);
                *(unsigned int*)(void*)(Pw + q * 128 + ((ue * 2) ^ ((q & 7) << 4))) = pk;
            }
        #pragma unroll
        for (int ks = 0; ks < 2; ks++) {
            int kb = ks * 64 + (g << 4);
            short8 pa = *(const short8*)(const void*)(Pw + q * 128 + (kb ^ ((q & 7) << 4)));
            #pragma unroll
            for (int f = 0; f < 4; f++) {
                int s = f * 16 + q;
                short8 vf = *(const short8*)(const void*)(Vb[bi] + s * 128 + (kb ^ ((s & 7) << 4)));
                oacc[f] = __builtin_amdgcn_mfma_f32_16x16x32_bf16(pa, vf, oacc[f], 0, 0, 0);
            }
        }
    }
    float inv = 1.0f / l_run;
    #pragma unroll
    for (int r = 0; r < 4; r++) {
        float ir = __shfl(inv, (lane & 48) | (g * 4 + r));
        int row_g = b * T_SEQ + qt * 64 + wave * 16 + g * 4 + r;
        #pragma unroll
        for (int f = 0; f < 4; f++) {
            size_t xi = (size_t)row_g * DMODEL + hh * HSZ + f * 16 + q;
            x[xi] += oacc[f][r] * ir;
        }
    }
}

// ---------------------------------------------------------------------------
// Loss: reduce per-strip {max,sumexp} partials -> nll[row]; then mean
// ---------------------------------------------------------------------------
__global__ __launch_bounds__(256) void loss_reduce_kernel(
    const float* __restrict__ pmax, const float* __restrict__ psum,
    const float* __restrict__ logits, const int* __restrict__ targets,
    float* __restrict__ nll)
{
    int row = blockIdx.x, tid = threadIdx.x;
    const float* pm = pmax + (size_t)row * NSTRIPS;
    const float* ps = psum + (size_t)row * NSTRIPS;
    float M = -1e30f, S = 0.f;
    for (int i = tid; i < NSTRIPS; i += 256) {
        float m2 = pm[i], s2 = ps[i];
        float nm = fmaxf(M, m2);
        S = S * __expf(M - nm) + s2 * __expf(m2 - nm);
        M = nm;
    }
    __shared__ float Ms[256], Ss[256];
    Ms[tid] = M; Ss[tid] = S;
    __syncthreads();
    for (int o = 128; o > 0; o >>= 1) {
        if (tid < o) {
            float m1 = Ms[tid], s1 = Ss[tid];
            float m2 = Ms[tid + o], s2 = Ss[tid + o];
            float nm = fmaxf(m1, m2);
            Ss[tid] = s1 * __expf(m1 - nm) + s2 * __expf(m2 - nm);
            Ms[tid] = nm;
        }
        __syncthreads();
    }
    if (tid == 0)
        nll[row] = logf(Ss[0]) + Ms[0] - logits[(size_t)row * VOCAB + targets[row]];
}

__global__ __launch_bounds__(256) void loss2_kernel(
    const float* __restrict__ nll, float* __restrict__ out)
{
    int tid = threadIdx.x;
    float s = 0.f;
    for (int i = tid; i < MROWS; i += 256) s += nll[i];
    __shared__ float red[256];
    red[tid] = s;
    __syncthreads();
    for (int o = 128; o > 0; o >>= 1) {
        if (tid < o) red[tid] += red[tid + o];
        __syncthreads();
    }
    if (tid == 0) out[0] = red[0] * (1.0f / MROWS);
}

// ---------------------------------------------------------------------------
extern "C" void kernel_launch(void* const* d_in, const int* in_sizes, int n_in,
                              void* d_out, int out_size, void* d_ws, size_t ws_size,
                              hipStream_t stream)
{
    const int*   idx  = (const int*)d_in[0];
    const int*   tgt  = (const int*)d_in[1];
    const float* tok  = (const float*)d_in[2];
    const float* pos  = (const float*)d_in[3];
    const float* Wq   = (const float*)d_in[4];
    const float* Wk   = (const float*)d_in[5];
    const float* Wv   = (const float*)d_in[6];
    const float* ln1g = (const float*)d_in[7];
    const float* ln1b = (const float*)d_in[8];
    const float* ln2g = (const float*)d_in[9];
    const float* ln2b = (const float*)d_in[10];
    const float* fc1w = (const float*)d_in[11];
    const float* fc1b = (const float*)d_in[12];
    const float* fc2w = (const float*)d_in[13];
    const float* fc2b = (const float*)d_in[14];
    const float* lnfg = (const float*)d_in[15];
    const float* lnfb = (const float*)d_in[16];
    const float* lmw  = (const float*)d_in[17];
    const float* lmb  = (const float*)d_in[18];

    char* ws = (char*)d_ws;
    float*          x    = (float*)(ws + 0);                  // 8.39 MB
    unsigned short* h    = (unsigned short*)(ws + 8388608);   // 4.19 MB
    unsigned short* qkv  = (unsigned short*)(ws + 12582912);  // 12.58 MB
    unsigned short* vt   = (unsigned short*)(ws + 25165824);  // 4.19 MB
    unsigned short* mid  = (unsigned short*)(ws + 29360128);  // 16.78 MB
    float*          nll  = (float*)(ws + 46137344);           // 8 KB
    float*          pmax = (float*)(ws + 46145536);           // 6.44 MB [2048][786]
    float*          psum = (float*)(ws + 52584448);           // 6.44 MB
    unsigned short* lmwt = (unsigned short*)(ws + 59023360);  // 103.02 MB [50304][1024]
    // end lmwt: 162045952
    const size_t UP_NEED = 438870016ull;
    bool upfront = (ws_size >= UP_NEED);
    unsigned short* qkvt = (unsigned short*)(ws + 162045952);
    unsigned short* fc1t, * fc2t;
    long qkvt_l, fc1t_l, fc2t_l;
    if (upfront) {
        fc1t = (unsigned short*)(ws + 237543424);
        fc2t = (unsigned short*)(ws + 338206720);
        qkvt_l = 3072 * 1024; fc1t_l = (long)FF * 1024; fc2t_l = (long)1024 * FF;
    } else {
        fc1t = (unsigned short*)(ws + 168337408);
        fc2t = (unsigned short*)(ws + 176726016);
        qkvt_l = 0; fc1t_l = 0; fc2t_l = 0;
    }
    float* logits = (float*)d_out;
    float* lossp  = logits + (size_t)MROWS * VOCAB;

    const long WQKV_L = (long)NHEAD * DMODEL * HSZ;
    if (upfront) {
        qkvpack_kernel<<<dim3(32, 2, 48 * NLAYER), 256, 0, stream>>>(
            Wq, Wk, Wv, qkvt, WQKV_L, qkvt_l);
        wtranspose_kernel<<<dim3(128, 32, NLAYER), 256, 0, stream>>>(
            fc1w, fc1t, DMODEL, FF, FF, (long)DMODEL * FF, fc1t_l);
        wtranspose_kernel<<<dim3(32, 128, NLAYER), 256, 0, stream>>>(
            fc2w, fc2t, FF, DMODEL, DMODEL, (long)FF * DMODEL, fc2t_l);
    }
    // LM head transpose with zero-padded cols [VOCAB, NPAD)
    wtranspose_kernel<<<dim3(1572, 32, 1), 256, 0, stream>>>(
        lmw, lmwt, DMODEL, VOCAB, NPAD, 0, 0);

    embed_kernel<<<MROWS, 256, 0, stream>>>(idx, tok, pos, x);

    for (int l = 0; l < NLAYER; l++) {
        unsigned short* qkvt_p = qkvt + (size_t)l * qkvt_l;
        unsigned short* fc1t_p = fc1t + (size_t)l * fc1t_l;
        unsigned short* fc2t_p = fc2t + (size_t)l * fc2t_l;
        if (!upfront) {
            qkvpack_kernel<<<dim3(32, 2, 48), 256, 0, stream>>>(
                Wq + (size_t)l * WQKV_L, Wk + (size_t)l * WQKV_L,
                Wv + (size_t)l * WQKV_L, qkvt, WQKV_L, 0);
            wtranspose_kernel<<<dim3(128, 32, 1), 256, 0, stream>>>(
                fc1w + (size_t)l * DMODEL * FF, fc1t, DMODEL, FF, FF, 0, 0);
            wtranspose_kernel<<<dim3(32, 128, 1), 256, 0, stream>>>(
                fc2w + (size_t)l * FF * DMODEL, fc2t, FF, DMODEL, DMODEL, 0, 0);
        }
        ln_kernel<<<MROWS, 256, 0, stream>>>(x, ln1g + l * DMODEL, ln1b + l * DMODEL, h);
        gemm_qkv<<<dim3(16, 24), 256, 0, stream>>>(h, qkvt_p, qkv, vt);
        attn_fused_kernel<<<dim3(4, NHEAD, 8), 256, 0, stream>>>(qkv, vt, x);
        ln_kernel<<<MROWS, 256, 0, stream>>>(x, ln2g + l * DMODEL, ln2b + l * DMODEL, h);
        gemm_fc1<<<dim3(16, 32), 256, 0, stream>>>(h, fc1t_p, fc1b + (size_t)l * FF, mid);
        gemm_fc2<<<dim3(32, 8), 256, 0, stream>>>(mid, fc2t_p, fc2b + (size_t)l * DMODEL, x, x);
    }

    ln_kernel<<<MROWS, 256, 0, stream>>>(x, lnfg, lnfb, h);
    gemm_lm<<<dim3(16, 393), 256, 0, stream>>>(h, lmwt, lmb, logits, pmax, psum);

    loss_reduce_kernel<<<MROWS, 256, 0, stream>>>(pmax, psum, logits, tgt, nll);
    loss2_kernel<<<1, 256, 0, stream>>>(nll, lossp);
}